// Round 1
// baseline (206.102 us; speedup 1.0000x reference)
//
#include <hip/hip_runtime.h>
#include <hip/hip_bf16.h>

// GroupLinear: out[t] = x[t] @ w[gid(t)].T
// T=8192, G=8, K=1024, N=2048; groups = contiguous token ranges (cum end-offs).
//
// R6 = pipeline rewrite of the GEMM (cvt + fallback unchanged from R5):
//  - BM=128, BN=256, BK=64, 512 threads (8 waves, 2Mx4N, per-wave 64x64 C).
//    Grid 8 x 72 = 576 blocks -> 2.25 blocks/CU (vs 256^2's pathological 1.22).
//  - TRIPLE-buffered LDS (3 x 48KB = 144KB) + counted s_waitcnt vmcnt(12):
//    tile t's loads issued at iter t-2, never drained to 0 in the main loop
//    (T3/T4; the old __syncthreads() forced vmcnt(0) every K-step -> 27% MfmaUtil).
//    Race-safety: stage(t+2) targets the buffer last READ at iter t-1, and is
//    issued only after iter t-1's end s_barrier; reads of tile t are gated by
//    own-wave vmcnt(12) + s_barrier (covers other waves' loads).
//  - T1 bijective XCD swizzle: all 8 n-blocks of a pair + 9 consecutive pairs
//    land on one XCD -> x-panel + per-expert w reuse in that XCD's L2.
//  - T5 setprio(1) around the MFMA cluster.
//  - Staging XOR swizzle, fragment reads, MFMA operand order, epilogue C/D
//    mapping and boundary row-masking are IDENTICAL to the verified R5 kernel.

#define T_DIM 8192
#define G_DIM 8
#define K_DIM 1024
#define N_DIM 2048
#define MAX_PAIRS 72        // 64 m-tiles(128) + <=7 boundary dups; %8==0 for swizzle
#define PPX (MAX_PAIRS / 8) // pairs per XCD chunk = 9
#define NT (K_DIM / 64)     // 16 K-tiles of BK=64

using short8  = __attribute__((ext_vector_type(8))) short;   // 8 bf16
using f32x4   = __attribute__((ext_vector_type(4))) float;   // MFMA acc / nt loads
using ushort8 = __attribute__((ext_vector_type(8))) unsigned short;

typedef __attribute__((address_space(1))) void gvoid;  // global
typedef __attribute__((address_space(3))) void lvoid;  // LDS

// ---------------- fp32 -> bf16 convert (grid-stride, 2x unroll, nt loads) ---
__global__ __launch_bounds__(256) void cvt_kernel(const float* __restrict__ x,
                                                  const float* __restrict__ w,
                                                  ushort8* __restrict__ xb,
                                                  ushort8* __restrict__ wb,
                                                  int n8x, int n8tot) {
  const int stride = gridDim.x * blockDim.x;
  for (int i = blockIdx.x * blockDim.x + threadIdx.x; i < n8tot; i += 2 * stride) {
#pragma unroll
    for (int u = 0; u < 2; ++u) {
      const int idx = i + u * stride;
      if (idx >= n8tot) break;
      const f32x4* s; ushort8* d; int j;
      if (idx < n8x) { s = (const f32x4*)x; d = xb; j = idx; }
      else           { s = (const f32x4*)w; d = wb; j = idx - n8x; }
      f32x4 v0 = __builtin_nontemporal_load(&s[2 * j]);
      f32x4 v1 = __builtin_nontemporal_load(&s[2 * j + 1]);
      ushort8 o;
      o[0] = __builtin_bit_cast(unsigned short, __float2bfloat16(v0[0]));
      o[1] = __builtin_bit_cast(unsigned short, __float2bfloat16(v0[1]));
      o[2] = __builtin_bit_cast(unsigned short, __float2bfloat16(v0[2]));
      o[3] = __builtin_bit_cast(unsigned short, __float2bfloat16(v0[3]));
      o[4] = __builtin_bit_cast(unsigned short, __float2bfloat16(v1[0]));
      o[5] = __builtin_bit_cast(unsigned short, __float2bfloat16(v1[1]));
      o[6] = __builtin_bit_cast(unsigned short, __float2bfloat16(v1[2]));
      o[7] = __builtin_bit_cast(unsigned short, __float2bfloat16(v1[3]));
      d[j] = o;
    }
  }
}

// ---------------- grouped bf16 GEMM: 128x256 tile, 3-buf counted pipeline ---
__global__ __launch_bounds__(512) void grouped_gemm_kernel(
    const __hip_bfloat16* __restrict__ xb,
    const __hip_bfloat16* __restrict__ wb,
    const int* __restrict__ offs,
    float* __restrict__ out) {
  // ---- T1: bijective XCD swizzle. HW linear id v = y*8+x; XCD ~ v%8.
  // XCD c gets pairs [c*9, c*9+9) x all 8 n-blocks -> x & w panels L2-local.
  const int v  = blockIdx.y * 8 + blockIdx.x;        // gridDim == (8, 72)
  const int p  = (v & 7) * PPX + ((v >> 3) % PPX);   // pair 0..71
  const int nb = (v >> 3) / PPX;                     // n-block 0..7
  const int n0 = nb * 256;

  // ---- map pair p -> (expert g, m-tile) via prefix sum of 128-row tile spans
  int offv[G_DIM];
#pragma unroll
  for (int i = 0; i < G_DIM; ++i) offv[i] = offs[i];

  int g = -1, tile = 0, lo = 0, hi = 0, pre = 0;
#pragma unroll
  for (int gi = 0; gi < G_DIM; ++gi) {
    const int l = gi ? offv[gi - 1] : 0;
    const int h = offv[gi];
    const int t0 = l >> 7;
    const int cnt = (h > l) ? (((h + 127) >> 7) - t0) : 0;
    if (g < 0 && p < pre + cnt) { g = gi; tile = t0 + (p - pre); lo = l; hi = h; }
    pre += cnt;
  }
  if (g < 0) return;  // dead pair (uniform per block; before any barrier)

  const int m0 = tile * 128;

  // 3 buffers: A 128x64 (8192 elems, 16KB), B 256x64 (16384 elems, 32KB)
  __shared__ __align__(16) __hip_bfloat16 As[3 * 128 * 64];   // 48 KB
  __shared__ __align__(16) __hip_bfloat16 Bs[3 * 256 * 64];   // 96 KB

  const __hip_bfloat16* wg = wb + (size_t)g * N_DIM * K_DIM;

  const int lane = threadIdx.x & 63;
  const int wid  = threadIdx.x >> 6;   // 0..7
  const int wm   = wid >> 2;           // 0..1 -> m offset 64
  const int wn   = wid & 3;            // 0..3 -> n offset 64

  // staging: chunk = 8 rows x 64 cols = 1KB; lane l -> LDS base + l*16B (linear).
  // row&7 == srow, so the XOR swizzle permutes the GLOBAL column block (rule 21:
  // linear dest + inverse-swizzled source + swizzled read).
  const int srow = lane >> 3;                  // row within chunk
  const int scol = ((lane & 7) ^ srow) * 8;    // swizzled global col (elems)

  // global sources at k-tile 0 (advance +64 elems per tile).
  // A: 16 chunks, 2/wave; B: 32 chunks, 4/wave.
  const __hip_bfloat16* gA0 = xb + (size_t)(m0 + (wid * 2 + 0) * 8 + srow) * K_DIM + scol;
  const __hip_bfloat16* gA1 = xb + (size_t)(m0 + (wid * 2 + 1) * 8 + srow) * K_DIM + scol;
  const __hip_bfloat16* gB0 = wg + (size_t)(n0 + (wid * 4 + 0) * 8 + srow) * K_DIM + scol;
  const __hip_bfloat16* gB1 = wg + (size_t)(n0 + (wid * 4 + 1) * 8 + srow) * K_DIM + scol;
  const __hip_bfloat16* gB2 = wg + (size_t)(n0 + (wid * 4 + 2) * 8 + srow) * K_DIM + scol;
  const __hip_bfloat16* gB3 = wg + (size_t)(n0 + (wid * 4 + 3) * 8 + srow) * K_DIM + scol;

  // LDS dests: wave-uniform chunk base + lane*16B (global_load_lds requirement)
  __hip_bfloat16* Ad = As + (wid * 2) * 512 + lane * 8;
  __hip_bfloat16* Bd = Bs + (wid * 4) * 512 + lane * 8;

  // 6 global_load_lds (width=16) per thread per K-tile
  auto stage = [&](int tt, int bb) {
    const int ko = tt * 64;
    __hip_bfloat16* Adb = Ad + bb * (128 * 64);
    __hip_bfloat16* Bdb = Bd + bb * (256 * 64);
    __builtin_amdgcn_global_load_lds((gvoid*)(gA0 + ko), (lvoid*)(Adb),        16, 0, 0);
    __builtin_amdgcn_global_load_lds((gvoid*)(gA1 + ko), (lvoid*)(Adb + 512),  16, 0, 0);
    __builtin_amdgcn_global_load_lds((gvoid*)(gB0 + ko), (lvoid*)(Bdb),        16, 0, 0);
    __builtin_amdgcn_global_load_lds((gvoid*)(gB1 + ko), (lvoid*)(Bdb + 512),  16, 0, 0);
    __builtin_amdgcn_global_load_lds((gvoid*)(gB2 + ko), (lvoid*)(Bdb + 1024), 16, 0, 0);
    __builtin_amdgcn_global_load_lds((gvoid*)(gB3 + ko), (lvoid*)(Bdb + 1536), 16, 0, 0);
  };

  f32x4 acc[4][4] = {};

  // 16 ds_read_b128 + 32 MFMA per wave per tile; swizzled read offsets match
  // the staging permutation (0 bank conflicts, verified in R5).
  auto compute_tile = [&](int bb) {
    const __hip_bfloat16* Ab = As + bb * (128 * 64);
    const __hip_bfloat16* Bb = Bs + bb * (256 * 64);
    short8 a[2][4], b[2][4];
#pragma unroll
    for (int ks = 0; ks < 2; ++ks) {
      const int kb  = ks * 4 + (lane >> 4);
      const int off = (kb ^ (lane & 7)) * 8;
#pragma unroll
      for (int mt = 0; mt < 4; ++mt)
        a[ks][mt] = *reinterpret_cast<const short8*>(
            Ab + (wm * 64 + mt * 16 + (lane & 15)) * 64 + off);
#pragma unroll
      for (int nt = 0; nt < 4; ++nt)
        b[ks][nt] = *reinterpret_cast<const short8*>(
            Bb + (wn * 64 + nt * 16 + (lane & 15)) * 64 + off);
    }
    __builtin_amdgcn_s_setprio(1);
#pragma unroll
    for (int ks = 0; ks < 2; ++ks)
#pragma unroll
      for (int mt = 0; mt < 4; ++mt)
#pragma unroll
        for (int nt = 0; nt < 4; ++nt)
          acc[mt][nt] = __builtin_amdgcn_mfma_f32_16x16x32_bf16(
              a[ks][mt], b[ks][nt], acc[mt][nt], 0, 0, 0);
    __builtin_amdgcn_s_setprio(0);
  };

  // ---- prologue: prefetch tiles 0,1
  stage(0, 0);
  stage(1, 1);

  // ---- main loop: stage t+2, wait OWN loads down to 12 (tiles t+1,t+2 in
  // flight -> tile t landed), barrier (covers other waves), compute, barrier
  // (tile t's buffer is the stage target of iter t+1).
  for (int t = 0; t < NT - 2; ++t) {
    const int buf = t % 3;
    stage(t + 2, (t + 2) % 3);
    asm volatile("s_waitcnt vmcnt(12)" ::: "memory");
    __builtin_amdgcn_s_barrier();
    asm volatile("" ::: "memory");
    compute_tile(buf);
    asm volatile("" ::: "memory");
    __builtin_amdgcn_s_barrier();
  }
  // ---- tail: no more stages; drain progressively
  asm volatile("s_waitcnt vmcnt(6)" ::: "memory");
  __builtin_amdgcn_s_barrier();
  asm volatile("" ::: "memory");
  compute_tile((NT - 2) % 3);
  asm volatile("s_waitcnt vmcnt(0)" ::: "memory");
  __builtin_amdgcn_s_barrier();
  asm volatile("" ::: "memory");
  compute_tile((NT - 1) % 3);

  // ---- epilogue: C/D layout col=lane&15, row=(lane>>4)*4+reg [m89-verified];
  // store only rows in [lo,hi) — boundary tiles written disjointly per expert.
  const int quad = lane >> 4;
#pragma unroll
  for (int mt = 0; mt < 4; ++mt) {
    const int rbase = m0 + wm * 64 + mt * 16 + quad * 4;
#pragma unroll
    for (int r = 0; r < 4; ++r) {
      const int row = rbase + r;
      if (row < lo || row >= hi) continue;
#pragma unroll
      for (int nt = 0; nt < 4; ++nt) {
        const int col = n0 + wn * 64 + nt * 16 + (lane & 15);
        out[(size_t)row * N_DIM + col] = acc[mt][nt][r];
      }
    }
  }
}

// ---------------- fp32 fallback (only if d_ws < 48 MB; correctness-only) ----
__global__ __launch_bounds__(256) void fallback_kernel(
    const float* __restrict__ x, const float* __restrict__ w,
    const int* __restrict__ offs, float* __restrict__ out) {
  __shared__ float xs[K_DIM];
  const int t = blockIdx.y;
  int g = 0;
  while (g < G_DIM - 1 && offs[g] <= t) ++g;
  for (int i = threadIdx.x; i < K_DIM; i += blockDim.x)
    xs[i] = x[(size_t)t * K_DIM + i];
  __syncthreads();
  const int n = blockIdx.x * blockDim.x + threadIdx.x;
  const float* wr = w + ((size_t)g * N_DIM + n) * K_DIM;
  float s = 0.f;
  for (int k = 0; k < K_DIM; ++k) s += xs[k] * wr[k];
  out[(size_t)t * N_DIM + n] = s;
}

extern "C" void kernel_launch(void* const* d_in, const int* in_sizes, int n_in,
                              void* d_out, int out_size, void* d_ws, size_t ws_size,
                              hipStream_t stream) {
  const float* x    = (const float*)d_in[0];
  const float* w    = (const float*)d_in[1];
  const int*   offs = (const int*)d_in[2];
  float*       out  = (float*)d_out;

  const size_t x_elems = (size_t)T_DIM * K_DIM;            // 8.39M
  const size_t w_elems = (size_t)G_DIM * N_DIM * K_DIM;    // 16.78M
  const size_t need    = (x_elems + w_elems) * sizeof(__hip_bfloat16);  // 48 MiB

  if (ws_size < need) {
    fallback_kernel<<<dim3(N_DIM / 256, T_DIM), 256, 0, stream>>>(x, w, offs, out);
    return;
  }

  __hip_bfloat16* xb = (__hip_bfloat16*)d_ws;
  __hip_bfloat16* wb = xb + x_elems;

  const int n8x   = (int)(x_elems / 8);              // 1,048,576
  const int n8tot = (int)((x_elems + w_elems) / 8);  // 3,145,728
  cvt_kernel<<<4096, 256, 0, stream>>>(x, w, (ushort8*)xb, (ushort8*)wb,
                                       n8x, n8tot);

  grouped_gemm_kernel<<<dim3(N_DIM / 256, MAX_PAIRS), 512, 0, stream>>>(
      xb, wb, offs, out);
}